// Round 1
// 2289.860 us; speedup vs baseline: 1.1002x; 1.1002x over previous
//
#include <hip/hip_runtime.h>
#include <stdint.h>

typedef unsigned short u16;
typedef __bf16 bf16x8 __attribute__((ext_vector_type(8)));
typedef __bf16 bf16x4 __attribute__((ext_vector_type(4)));
typedef float f32x4 __attribute__((ext_vector_type(4)));

__device__ __forceinline__ float b2f(u16 b) {
    return __builtin_bit_cast(float, ((unsigned)b) << 16);
}
__device__ __forceinline__ u16 f2b(float f) {
    unsigned u = __builtin_bit_cast(unsigned, f);
    return (u16)((u + 0x7fffu + ((u >> 16) & 1u)) >> 16);
}
__device__ __forceinline__ void async16(const void* g, void* l) {
    __builtin_amdgcn_global_load_lds((const __attribute__((address_space(1))) void*)g,
                                     (__attribute__((address_space(3))) void*)l, 16, 0, 0);
}

// ---------------------------------------------------------------- add pe (f32 in)
__global__ __launch_bounds__(256) void add_pe_kernel(const float* __restrict__ x,
                                                     const float* __restrict__ pe,
                                                     float* __restrict__ hf,
                                                     u16* __restrict__ hb) {
    const size_t i = ((size_t)blockIdx.x * 256 + threadIdx.x) * 4;
    float4 xv = *(const float4*)(x + i);
    float4 pv = *(const float4*)(pe + (i & 2097151));  // i mod L*D (2^21)
    float4 f;
    f.x = xv.x + pv.x; f.y = xv.y + pv.y; f.z = xv.z + pv.z; f.w = xv.w + pv.w;
    *(float4*)(hf + i) = f;
    ushort4 hv;
    hv.x = f2b(f.x); hv.y = f2b(f.y); hv.z = f2b(f.z); hv.w = f2b(f.w);
    *(ushort4*)(hb + i) = hv;
}

// ------------------------------------------- transpose+cast: src f32 [K, srcStride] -> dst bf16 [N, K]
__global__ __launch_bounds__(256) void transpose_cast_kernel(const float* __restrict__ src,
                                                             u16* __restrict__ dst,
                                                             int srcStride, int K) {
    __shared__ __align__(16) u16 tile[64 * 72];
    const int n0 = blockIdx.x * 64, k0 = blockIdx.y * 64;
    const int t = threadIdx.x;
    const int r = t >> 3, c8 = (t & 7) * 8;
#pragma unroll
    for (int ph = 0; ph < 2; ph++) {
        const int rr = r + ph * 32;
        const float* s = src + (size_t)(k0 + rr) * srcStride + n0 + c8;
        float4 a = *(const float4*)s;
        float4 b = *(const float4*)(s + 4);
        u16* tr = tile + rr * 72 + c8;
        tr[0] = f2b(a.x); tr[1] = f2b(a.y); tr[2] = f2b(a.z); tr[3] = f2b(a.w);
        tr[4] = f2b(b.x); tr[5] = f2b(b.y); tr[6] = f2b(b.z); tr[7] = f2b(b.w);
    }
    __syncthreads();
#pragma unroll
    for (int ph = 0; ph < 2; ph++) {
        const int rr = r + ph * 32;
        union { float4 f; u16 u[8]; } ov;
#pragma unroll
        for (int j = 0; j < 8; j++) ov.u[j] = tile[(c8 + j) * 72 + rr];
        *(float4*)(dst + (size_t)(n0 + rr) * K + k0 + c8) = ov.f;
    }
}

// ------------------------------------------- fused QKV weight transpose: 3 x [1024,1024] f32 -> bf16^T
__global__ __launch_bounds__(256) void transpose_qkv_kernel(const float* __restrict__ wq,
                                                            const float* __restrict__ wk,
                                                            const float* __restrict__ wv,
                                                            u16* __restrict__ dst) {
    __shared__ __align__(16) u16 tile[64 * 72];
    const float* src = (blockIdx.z == 0) ? wq : (blockIdx.z == 1) ? wk : wv;
    u16* d = dst + (size_t)blockIdx.z * 1048576;
    const int n0 = blockIdx.x * 64, k0 = blockIdx.y * 64;
    const int t = threadIdx.x;
    const int r = t >> 3, c8 = (t & 7) * 8;
#pragma unroll
    for (int ph = 0; ph < 2; ph++) {
        const int rr = r + ph * 32;
        const float* s = src + (size_t)(k0 + rr) * 1024 + n0 + c8;
        float4 a = *(const float4*)s;
        float4 b = *(const float4*)(s + 4);
        u16* tr = tile + rr * 72 + c8;
        tr[0] = f2b(a.x); tr[1] = f2b(a.y); tr[2] = f2b(a.z); tr[3] = f2b(a.w);
        tr[4] = f2b(b.x); tr[5] = f2b(b.y); tr[6] = f2b(b.z); tr[7] = f2b(b.w);
    }
    __syncthreads();
#pragma unroll
    for (int ph = 0; ph < 2; ph++) {
        const int rr = r + ph * 32;
        union { float4 f; u16 u[8]; } ov;
#pragma unroll
        for (int j = 0; j < 8; j++) ov.u[j] = tile[(c8 + j) * 72 + rr];
        *(float4*)(d + (size_t)(n0 + rr) * 1024 + k0 + c8) = ov.f;
    }
}

// ------------------------------------------- per-head V transpose: [bh][t][64] -> [bh][64][t] (bf16)
__global__ __launch_bounds__(256) void transpose_v_kernel(const u16* __restrict__ src,
                                                          u16* __restrict__ dst) {
    __shared__ __align__(16) u16 tile[64 * 72];
    const int bh = blockIdx.y, t0 = blockIdx.x * 64;
    const int t = threadIdx.x;
    const int r = t >> 3, c8 = (t & 7) * 8;
    const size_t base = (size_t)bh * 131072;
#pragma unroll
    for (int ph = 0; ph < 2; ph++) {
        const int rr = r + ph * 32;
        *(float4*)(tile + rr * 72 + c8) = *(const float4*)(src + base + (size_t)(t0 + rr) * 64 + c8);
    }
    __syncthreads();
#pragma unroll
    for (int ph = 0; ph < 2; ph++) {
        const int rr = r + ph * 32;  // d row
        union { float4 f; u16 u[8]; } ov;
#pragma unroll
        for (int j = 0; j < 8; j++) ov.u[j] = tile[(c8 + j) * 72 + rr];
        *(float4*)(dst + base + (size_t)rr * 2048 + t0 + c8) = ov.f;
    }
}

// ---------------------------------------------------------------- legacy GEMM C = A[M,K] * BT[N,K]^T
// (kept for FFN2: N=1024 is shape-poor for 256x256 tiles). MODE 2: bias -> f32 O0[M,N]
template <int MODE, int MTILES>
__global__ __launch_bounds__(256, 2) void gemm_kernel(const u16* __restrict__ A,
                                                      const u16* __restrict__ BT,
                                                      const float* __restrict__ bias,
                                                      void* __restrict__ O0, void* __restrict__ O1,
                                                      void* __restrict__ O2, int N, int K) {
    __shared__ __align__(16) u16 As[MTILES * 32 * 32];
    __shared__ __align__(16) u16 Bs[128 * 32];
    const int tid = threadIdx.x;
    const int lane = tid & 63, w = tid >> 6, quad = lane >> 4, l15 = lane & 15;
    const int m0 = blockIdx.y * (MTILES * 32), n0 = blockIdx.x * 128;
    const int wm = w >> 1, wn = w & 1;

    f32x4 acc[MTILES][4] = {};

    const int srow = tid >> 2, scol = (tid & 3) * 8;
    const u16* Ag = A + (size_t)(m0 + srow) * K + scol;
    const u16* Bg = BT + (size_t)(n0 + srow) * K + scol;
    u16* Asd = As + tid * 8;
    u16* Bsd = Bs + tid * 8;
    const size_t half = (size_t)64 * K;

    for (int k0 = 0; k0 < K; k0 += 32) {
        __syncthreads();
#pragma unroll
        for (int i = 0; i < MTILES / 2; i++) async16(Ag + k0 + i * half, Asd + i * 2048);
        async16(Bg + k0, Bsd);
        async16(Bg + k0 + half, Bsd + 2048);
        __syncthreads();
        bf16x8 af[MTILES], bfr[4];
#pragma unroll
        for (int mt = 0; mt < MTILES; mt++)
            af[mt] = *(const bf16x8*)(As + (wm * (MTILES * 16) + mt * 16 + l15) * 32 + quad * 8);
#pragma unroll
        for (int nt = 0; nt < 4; nt++)
            bfr[nt] = *(const bf16x8*)(Bs + (wn * 64 + nt * 16 + l15) * 32 + quad * 8);
#pragma unroll
        for (int mt = 0; mt < MTILES; mt++)
#pragma unroll
            for (int nt = 0; nt < 4; nt++)
                acc[mt][nt] = __builtin_amdgcn_mfma_f32_16x16x32_bf16(af[mt], bfr[nt], acc[mt][nt], 0, 0, 0);
    }

#pragma unroll
    for (int nt = 0; nt < 4; nt++) {
        const int col = n0 + wn * 64 + nt * 16 + l15;
        float bv = 0.f;
        if (MODE == 1 || MODE == 2) bv = bias[col];
#pragma unroll
        for (int mt = 0; mt < MTILES; mt++) {
#pragma unroll
            for (int r = 0; r < 4; r++) {
                const int row = m0 + wm * (MTILES * 16) + mt * 16 + quad * 4 + r;
                float val = acc[mt][nt][r];
                if (MODE == 1) {
                    val += bv;
                    const float s = 1.0507009873554805f, a = 1.6732632423543772f;
                    val = val > 0.f ? s * val : s * a * (__expf(val) - 1.f);
                    ((u16*)O0)[(size_t)row * N + col] = f2b(val);
                } else if (MODE == 2) {
                    ((float*)O0)[(size_t)row * N + col] = val + bv;
                } else {
                    ((float*)O0)[(size_t)row * N + col] += val;
                }
            }
        }
    }
}

// ---------------------------------------------------------------- 256x256 8-phase GEMM, BK=64
// C = A[M,K] * BT[N,K]^T. 8 waves (2M x 4N), per-wave 128x64 output. LDS 128KB:
// [buf(2)][A|B][kh(2)][256 rows][32 bf16] with 16B-granule XOR swizzle slot^=(row>>1)&3
// (applied via pre-swizzled GLOBAL source so global_load_lds dest stays linear).
// Schedule (paper-verified dead/land analysis): per K-tile t, 4 phases (kh,mh) =
// (0,0),(1,0),(0,1),(1,1); stages: phi0->Akh1(t+1), phi1->Bkh0(t+2), phi2->Bkh1(t+2),
// phi3->Akh0(t+2); vmcnt(6) once per tile at phi3 (exactly: issued-6 == Akh1(t+1)),
// vmcnt(0) at t==NT-2. Counted vmcnt never drains in steady state (T3+T4); setprio
// around MFMA clusters (T5).
// MODE 0: QKV scatter (q pre-scaled by 0.125*log2(e)); MODE 1: bias+selu bf16; MODE 2: bias f32.
#define G_SYNC1()                                          \
    __builtin_amdgcn_sched_barrier(0);                     \
    __builtin_amdgcn_s_barrier();                          \
    asm volatile("s_waitcnt lgkmcnt(0)" ::: "memory");     \
    __builtin_amdgcn_sched_barrier(0);                     \
    __builtin_amdgcn_s_setprio(1)
#define G_SYNC2()                                          \
    __builtin_amdgcn_s_setprio(0);                         \
    __builtin_amdgcn_sched_barrier(0);                     \
    __builtin_amdgcn_s_barrier()

template <int MODE, int NT>
__global__ __launch_bounds__(512) void gemm256_kernel(const u16* __restrict__ A,
                                                      const u16* __restrict__ BT,
                                                      const float* __restrict__ bias,
                                                      void* __restrict__ O0, void* __restrict__ O1,
                                                      void* __restrict__ O2, int N) {
    constexpr int K = NT * 64;
    __shared__ __align__(16) u16 lds[65536];  // 128 KB
    const int tid = threadIdx.x;
    const int lane = tid & 63, w = tid >> 6, quad = lane >> 4, l15 = lane & 15;
    const int wm = w >> 2, wn = w & 3;
    const int m0 = blockIdx.y * 256, n0 = blockIdx.x * 256;

    f32x4 acc[8][4] = {};

    // staging: thread t covers granule t (rows 0-127) and 512+t (rows 128-255) of a kh-block
    const int srow = tid >> 2;
    const int slog = (tid & 3) ^ ((tid >> 3) & 3);  // pre-swizzled source slot
    const u16* pA = A + (size_t)(m0 + srow) * K + slog * 8;
    const u16* pB = BT + (size_t)(n0 + srow) * K + slog * 8;
    u16* const ldst = lds + tid * 8;

    // frag-read bases (swizzle key (row>>1)&3 == (l15>>1)&3 since row offsets are x16)
    const int swz = (quad ^ ((l15 >> 1) & 3)) * 8;
    const int aro = (wm * 128 + l15) * 32 + swz;           // + boff + kh*8192 + mh*2048 + mt*512
    const int bro = 16384 + (wn * 64 + l15) * 32 + swz;    // + boff + kh*8192 + nt*512

    auto stA = [&](int tt, int kh) {
        u16* d = ldst + ((tt & 1) << 15) + (kh << 13);
        const u16* s = pA + tt * 64 + kh * 32;
        async16(s, d);
        async16(s + (size_t)128 * K, d + 4096);
    };
    auto stB = [&](int tt, int kh) {
        u16* d = ldst + ((tt & 1) << 15) + 16384 + (kh << 13);
        const u16* s = pB + tt * 64 + kh * 32;
        async16(s, d);
        async16(s + (size_t)128 * K, d + 4096);
    };

    // prologue: tile0 fully, tile1 all but Akh1 (14 per-thread loads)
    stB(0, 0); stB(0, 1); stA(0, 0); stA(0, 1);
    stB(1, 0); stB(1, 1); stA(1, 0);
    asm volatile("s_waitcnt vmcnt(6)" ::: "memory");  // tile0's 8 loads landed
    __builtin_amdgcn_s_barrier();

#pragma unroll 2
    for (int t = 0; t < NT; ++t) {
        const int boff = (t & 1) << 15;
        bf16x8 a[4], bk0[4], bk1[4];
        // ---- phase 0: (kh0, mh0); B kh0 into regs; stage Akh1(t+1)
#pragma unroll
        for (int i = 0; i < 4; i++) a[i] = *(const bf16x8*)(lds + boff + aro + i * 512);
#pragma unroll
        for (int i = 0; i < 4; i++) bk0[i] = *(const bf16x8*)(lds + boff + bro + i * 512);
        if (t + 1 < NT) stA(t + 1, 1);
        G_SYNC1();
#pragma unroll
        for (int mt = 0; mt < 4; mt++)
#pragma unroll
            for (int nt = 0; nt < 4; nt++)
                acc[mt][nt] = __builtin_amdgcn_mfma_f32_16x16x32_bf16(a[mt], bk0[nt], acc[mt][nt], 0, 0, 0);
        G_SYNC2();
        // ---- phase 1: (kh1, mh0); B kh1 into regs; stage Bkh0(t+2)
#pragma unroll
        for (int i = 0; i < 4; i++) a[i] = *(const bf16x8*)(lds + boff + 8192 + aro + i * 512);
#pragma unroll
        for (int i = 0; i < 4; i++) bk1[i] = *(const bf16x8*)(lds + boff + 8192 + bro + i * 512);
        if (t + 2 < NT) stB(t + 2, 0);
        G_SYNC1();
#pragma unroll
        for (int mt = 0; mt < 4; mt++)
#pragma unroll
            for (int nt = 0; nt < 4; nt++)
                acc[mt][nt] = __builtin_amdgcn_mfma_f32_16x16x32_bf16(a[mt], bk1[nt], acc[mt][nt], 0, 0, 0);
        G_SYNC2();
        // ---- phase 2: (kh0, mh1); reuse bk0; stage Bkh1(t+2)
#pragma unroll
        for (int i = 0; i < 4; i++) a[i] = *(const bf16x8*)(lds + boff + aro + 2048 + i * 512);
        if (t + 2 < NT) stB(t + 2, 1);
        G_SYNC1();
#pragma unroll
        for (int mt = 0; mt < 4; mt++)
#pragma unroll
            for (int nt = 0; nt < 4; nt++)
                acc[4 + mt][nt] = __builtin_amdgcn_mfma_f32_16x16x32_bf16(a[mt], bk0[nt], acc[4 + mt][nt], 0, 0, 0);
        G_SYNC2();
        // ---- phase 3: (kh1, mh1); reuse bk1; stage Akh0(t+2); per-tile vmcnt
#pragma unroll
        for (int i = 0; i < 4; i++) a[i] = *(const bf16x8*)(lds + boff + 8192 + aro + 2048 + i * 512);
        if (t + 2 < NT) stA(t + 2, 0);
        G_SYNC1();
#pragma unroll
        for (int mt = 0; mt < 4; mt++)
#pragma unroll
            for (int nt = 0; nt < 4; nt++)
                acc[4 + mt][nt] = __builtin_amdgcn_mfma_f32_16x16x32_bf16(a[mt], bk1[nt], acc[4 + mt][nt], 0, 0, 0);
        __builtin_amdgcn_s_setprio(0);
        __builtin_amdgcn_sched_barrier(0);
        if (t < NT - 2) {
            asm volatile("s_waitcnt vmcnt(6)" ::: "memory");  // tile t+1 fully landed
        } else if (t == NT - 2) {
            asm volatile("s_waitcnt vmcnt(0)" ::: "memory");  // tail: drain last tile
        }
        __builtin_amdgcn_sched_barrier(0);
        __builtin_amdgcn_s_barrier();
    }

#pragma unroll
    for (int nt = 0; nt < 4; nt++) {
        const int col = n0 + wn * 64 + nt * 16 + l15;
        float bv = 0.f;
        if (MODE == 1 || MODE == 2) bv = bias[col];
#pragma unroll
        for (int am = 0; am < 8; am++) {
#pragma unroll
            for (int r = 0; r < 4; r++) {
                const int row = m0 + wm * 128 + am * 16 + quad * 4 + r;
                float val = acc[am][nt][r];
                if (MODE == 0) {
                    const int mat = col >> 10, cc = col & 1023;
                    const int head = cc >> 6, dh = cc & 63;
                    const int b = row >> 11, tt = row & 2047;
                    if (mat == 0) val *= 0.18033688f;  // 0.125 * log2(e): base-2 softmax domain
                    u16* dst = (mat == 0) ? (u16*)O0 : (mat == 1) ? (u16*)O1 : (u16*)O2;
                    dst[(((size_t)(b * 16 + head)) * 2048 + tt) * 64 + dh] = f2b(val);
                } else if (MODE == 1) {
                    val += bv;
                    const float s = 1.0507009873554805f, aa = 1.6732632423543772f;
                    val = val > 0.f ? s * val : s * aa * (__expf(val) - 1.f);
                    ((u16*)O0)[(size_t)row * N + col] = f2b(val);
                } else if (MODE == 2) {
                    ((float*)O0)[(size_t)row * N + col] = val + bv;
                }
            }
        }
    }
}

// ---------------------------------------------------------------- flash attention (causal), S^T form
__global__ __launch_bounds__(256) void attn_kernel(const u16* __restrict__ q,
                                                   const u16* __restrict__ k,
                                                   const u16* __restrict__ vT,
                                                   u16* __restrict__ o) {
    __shared__ __align__(16) u16 Kt[64 * 72];      // [k][d]
    __shared__ __align__(16) u16 Vt[64 * 72];      // [d][k]
    __shared__ __align__(16) u16 Pt[4][32 * 72];   // per-wave P [q][k]
    const int tid = threadIdx.x, lane = tid & 63, w = tid >> 6, quad = lane >> 4, l15 = lane & 15;
    const int bh = blockIdx.x;
    const int qt = 15 - blockIdx.y;                // LPT: heavy diagonal blocks dispatch first
    const size_t base = (size_t)bh * 131072;
    const int wrow0 = qt * 128 + w * 32;

    bf16x8 qf[2][2];
#pragma unroll
    for (int nt = 0; nt < 2; nt++)
#pragma unroll
        for (int ks = 0; ks < 2; ks++)
            qf[nt][ks] = *(const bf16x8*)(q + base + (size_t)(wrow0 + nt * 16 + l15) * 64 + ks * 32 + quad * 8);

    float m_[2], l_[2];
    m_[0] = m_[1] = -1e30f;
    l_[0] = l_[1] = 0.f;
    f32x4 oacc[2][4] = {};

    const int ktmax = (qt + 1) * 2;
    const int srow = tid >> 3, sc8 = (tid & 7) * 8;

    for (int kt = 0; kt < ktmax; kt++) {
        __syncthreads();
#pragma unroll
        for (int ph = 0; ph < 2; ph++) {
            const int rr = srow + ph * 32;
            *(float4*)(Kt + rr * 72 + sc8) = *(const float4*)(k + base + (size_t)(kt * 64 + rr) * 64 + sc8);
            *(float4*)(Vt + rr * 72 + sc8) = *(const float4*)(vT + base + (size_t)rr * 2048 + kt * 64 + sc8);
        }
        __syncthreads();
        const bool act = (kt * 64 <= wrow0 + 31);
        if (act) {
            f32x4 st[4][2];
#pragma unroll
            for (int mt = 0; mt < 4; mt++) {
                bf16x8 kf0 = *(const bf16x8*)(Kt + (mt * 16 + l15) * 72 + quad * 8);
                bf16x8 kf1 = *(const bf16x8*)(Kt + (mt * 16 + l15) * 72 + 32 + quad * 8);
#pragma unroll
                for (int nt = 0; nt < 2; nt++) {
                    f32x4 z = {};
                    z = __builtin_amdgcn_mfma_f32_16x16x32_bf16(kf0, qf[nt][0], z, 0, 0, 0);
                    z = __builtin_amdgcn_mfma_f32_16x16x32_bf16(kf1, qf[nt][1], z, 0, 0, 0);
                    st[mt][nt] = z;
                }
            }
            const bool needmask = (kt * 64 + 63 > wrow0);
            float alpha[2];
#pragma unroll
            for (int nt = 0; nt < 2; nt++) {
                const int qg = wrow0 + nt * 16 + l15;
                float mx = -1e30f;
                if (needmask) {
#pragma unroll
                    for (int mt = 0; mt < 4; mt++)
#pragma unroll
                        for (int r = 0; r < 4; r++) {
                            const int kg = kt * 64 + mt * 16 + quad * 4 + r;
                            float s = (kg <= qg) ? st[mt][nt][r] : -1e30f;
                            st[mt][nt][r] = s;
                            mx = fmaxf(mx, s);
                        }
                } else {
#pragma unroll
                    for (int mt = 0; mt < 4; mt++)
#pragma unroll
                        for (int r = 0; r < 4; r++) mx = fmaxf(mx, st[mt][nt][r]);
                }
                mx = fmaxf(mx, __shfl_xor(mx, 16, 64));
                mx = fmaxf(mx, __shfl_xor(mx, 32, 64));
                const float mnew = fmaxf(m_[nt], mx);
                alpha[nt] = exp2f(m_[nt] - mnew);
                m_[nt] = mnew;
                float rs = 0.f;
#pragma unroll
                for (int mt = 0; mt < 4; mt++) {
                    float p0 = exp2f(st[mt][nt][0] - mnew);
                    float p1 = exp2f(st[mt][nt][1] - mnew);
                    float p2 = exp2f(st[mt][nt][2] - mnew);
                    float p3 = exp2f(st[mt][nt][3] - mnew);
                    rs += (p0 + p1) + (p2 + p3);
                    bf16x4 pk = {(__bf16)p0, (__bf16)p1, (__bf16)p2, (__bf16)p3};
                    *(bf16x4*)(Pt[w] + (nt * 16 + l15) * 72 + mt * 16 + quad * 4) = pk;
                }
                rs += __shfl_xor(rs, 16, 64);
                rs += __shfl_xor(rs, 32, 64);
                l_[nt] = l_[nt] * alpha[nt] + rs;
            }
            float arow[2][4];
#pragma unroll
            for (int mto = 0; mto < 2; mto++)
#pragma unroll
                for (int r = 0; r < 4; r++)
                    arow[mto][r] = __shfl(alpha[mto], quad * 4 + r, 64);
#pragma unroll
            for (int mto = 0; mto < 2; mto++)
#pragma unroll
                for (int ntv = 0; ntv < 4; ntv++)
#pragma unroll
                    for (int r = 0; r < 4; r++) oacc[mto][ntv][r] *= arow[mto][r];

            bf16x8 pf[2][2];
#pragma unroll
            for (int mto = 0; mto < 2; mto++)
#pragma unroll
                for (int ks = 0; ks < 2; ks++)
                    pf[mto][ks] = *(const bf16x8*)(Pt[w] + (mto * 16 + l15) * 72 + ks * 32 + quad * 8);
#pragma unroll
            for (int ntv = 0; ntv < 4; ntv++) {
                bf16x8 vf0 = *(const bf16x8*)(Vt + (ntv * 16 + l15) * 72 + quad * 8);
                bf16x8 vf1 = *(const bf16x8*)(Vt + (ntv * 16 + l15) * 72 + 32 + quad * 8);
#pragma unroll
                for (int mto = 0; mto < 2; mto++) {
                    oacc[mto][ntv] = __builtin_amdgcn_mfma_f32_16x16x32_bf16(pf[mto][0], vf0, oacc[mto][ntv], 0, 0, 0);
                    oacc[mto][ntv] = __builtin_amdgcn_mfma_f32_16x16x32_bf16(pf[mto][1], vf1, oacc[mto][ntv], 0, 0, 0);
                }
            }
        }
    }

    float linv[2] = {1.f / l_[0], 1.f / l_[1]};
    float rinv[2][4];
#pragma unroll
    for (int mto = 0; mto < 2; mto++)
#pragma unroll
        for (int r = 0; r < 4; r++)
            rinv[mto][r] = __shfl(linv[mto], quad * 4 + r, 64);

    const int b = bh >> 4, hh = bh & 15;
#pragma unroll
    for (int mto = 0; mto < 2; mto++)
#pragma unroll
        for (int ntv = 0; ntv < 4; ntv++)
#pragma unroll
            for (int r = 0; r < 4; r++) {
                const int trow = wrow0 + mto * 16 + quad * 4 + r;
                const int col = hh * 64 + ntv * 16 + l15;
                o[((size_t)b * 2048 + trow) * 1024 + col] = f2b(oacc[mto][ntv][r] * rinv[mto][r]);
            }
}

// ---------------------------------------------------------------- fused residual-add + layernorm
template <int ADD_BF16>
__global__ __launch_bounds__(256) void ln_kernel(const float* __restrict__ hin,
                                                 const void* __restrict__ addp,
                                                 const float* __restrict__ g,
                                                 const float* __restrict__ bt,
                                                 float* __restrict__ hf_out,
                                                 u16* __restrict__ hb_out) {
    const int w = threadIdx.x >> 6, lane = threadIdx.x & 63;
    const size_t row = (size_t)blockIdx.x * 4 + w;
    const float4* hr = (const float4*)(hin + row * 1024);
    float4 xv[4];
    float s = 0.f, s2 = 0.f;
#pragma unroll
    for (int j = 0; j < 4; j++) {
        const int idx = lane + 64 * j;
        float4 a = hr[idx];
        float4 b;
        if (ADD_BF16) {
            ushort4 av = ((const ushort4*)addp)[row * 256 + idx];
            b.x = b2f(av.x); b.y = b2f(av.y); b.z = b2f(av.z); b.w = b2f(av.w);
        } else {
            b = ((const float4*)addp)[row * 256 + idx];
        }
        float4 x;
        x.x = a.x + b.x; x.y = a.y + b.y; x.z = a.z + b.z; x.w = a.w + b.w;
        xv[j] = x;
        s += x.x + x.y + x.z + x.w;
        s2 += x.x * x.x + x.y * x.y + x.z * x.z + x.w * x.w;
    }
#pragma unroll
    for (int mm = 1; mm < 64; mm <<= 1) { s += __shfl_xor(s, mm, 64); s2 += __shfl_xor(s2, mm, 64); }
    const float mean = s * (1.f / 1024.f);
    const float var = s2 * (1.f / 1024.f) - mean * mean;
    const float rstd = rsqrtf(var + 1e-5f);
    float4* of = (float4*)(hf_out + row * 1024);
    ushort4* ob = (ushort4*)(hb_out + row * 1024);
    const float4* gv = (const float4*)g;
    const float4* bv = (const float4*)bt;
#pragma unroll
    for (int j = 0; j < 4; j++) {
        const int idx = lane + 64 * j;
        float4 gg = gv[idx], bb = bv[idx];
        float4 x = xv[j], y;
        y.x = (x.x - mean) * rstd * gg.x + bb.x;
        y.y = (x.y - mean) * rstd * gg.y + bb.y;
        y.z = (x.z - mean) * rstd * gg.z + bb.z;
        y.w = (x.w - mean) * rstd * gg.w + bb.w;
        of[idx] = y;
        ushort4 oo;
        oo.x = f2b(y.x); oo.y = f2b(y.y); oo.z = f2b(y.z); oo.w = f2b(y.w);
        ob[idx] = oo;
    }
}

// ---------------------------------------------------------------- host
extern "C" void kernel_launch(void* const* d_in, const int* in_sizes, int n_in,
                              void* d_out, int out_size, void* d_ws, size_t ws_size,
                              hipStream_t stream) {
    const float* x   = (const float*)d_in[0];
    const float* pe  = (const float*)d_in[1];
    const float* wq  = (const float*)d_in[2];
    const float* wk  = (const float*)d_in[3];
    const float* wv  = (const float*)d_in[4];
    const float* l1g = (const float*)d_in[5];
    const float* l1b = (const float*)d_in[6];
    const float* w1  = (const float*)d_in[7];
    const float* b1  = (const float*)d_in[8];
    const float* w2  = (const float*)d_in[9];
    const float* b2  = (const float*)d_in[10];
    const float* l2g = (const float*)d_in[11];
    const float* l2b = (const float*)d_in[12];

    // 126 MB workspace (poison memset shows ws = 512 MB):
    char* ws = (char*)d_ws;
    float* hf   = (float*)(ws);                   // [  0, 16M) f32 residual stream
    u16* hb     = (u16*)(ws + 16777216);          // [ 16, 24M) bf16 mirror of h
    u16* qb     = (u16*)(ws + 25165824);          // [ 24, 32M) Q bf16 (pre-scaled)
    u16* kb     = (u16*)(ws + 33554432);          // [ 32, 40M) K bf16
    u16* vb     = (u16*)(ws + 41943040);          // [ 40, 48M) V bf16 natural [bh][t][d]
    u16* vbt    = (u16*)(ws + 50331648);          // [ 48, 56M) V^T [bh][d][t]
    u16* ob     = (u16*)(ws + 41943040);          // [ 40, 48M) attn out (aliases vb; dead after transpose_v)
    u16* wqkvT  = (u16*)(ws + 58720256);          // [ 56, 62M) qkv weights^T bf16 [3072,1024]
    u16* w1T    = (u16*)(ws + 65011712);          // [ 62, 70M) w1^T bf16 [4096,1024]
    u16* w2T    = (u16*)(ws + 73400320);          // [ 70, 78M) w2^T bf16 [1024,4096]
    u16* ub     = (u16*)(ws + 81788928);          // [ 78,110M) ffn hidden bf16 [4096,4096]
    float* mb   = (float*)(ws + 115343360);       // [110,126M) ffn out f32

    add_pe_kernel<<<4096, 256, 0, stream>>>(x, pe, hf, hb);

    for (int l = 0; l < 8; l++) {
        // --- QKV ---
        transpose_qkv_kernel<<<dim3(16, 16, 3), 256, 0, stream>>>(
            wq + (size_t)l * 1048576, wk + (size_t)l * 1048576, wv + (size_t)l * 1048576, wqkvT);
        gemm256_kernel<0, 16><<<dim3(12, 16), 512, 0, stream>>>(hb, wqkvT, nullptr, qb, kb, vb, 3072);
        transpose_v_kernel<<<dim3(32, 32), 256, 0, stream>>>(vb, vbt);
        // --- attention ---
        attn_kernel<<<dim3(32, 16), 256, 0, stream>>>(qb, kb, vbt, ob);
        ln_kernel<1><<<1024, 256, 0, stream>>>(hf, ob, l1g + l * 1024, l1b + l * 1024, hf, hb);
        // --- FFN, full width ---
        transpose_cast_kernel<<<dim3(64, 16), 256, 0, stream>>>(w1 + (size_t)l * 4194304, w1T, 4096, 1024);
        gemm256_kernel<1, 16><<<dim3(16, 16), 512, 0, stream>>>(hb, w1T, b1 + l * 4096, ub, nullptr, nullptr, 4096);
        transpose_cast_kernel<<<dim3(16, 64), 256, 0, stream>>>(w2 + (size_t)l * 4194304, w2T, 1024, 4096);
        gemm_kernel<2, 2><<<dim3(8, 64), 256, 0, stream>>>(ub, w2T, b2 + l * 1024, mb, nullptr, nullptr, 1024, 4096);
        const bool last = (l == 7);
        ln_kernel<0><<<1024, 256, 0, stream>>>(hf, mb, l2g + l * 1024, l2b + l * 1024,
                                               last ? (float*)d_out : hf, hb);
    }
}

// Round 2
// 2189.617 us; speedup vs baseline: 1.1506x; 1.0458x over previous
//
#include <hip/hip_runtime.h>
#include <stdint.h>

typedef unsigned short u16;
typedef __bf16 bf16x8 __attribute__((ext_vector_type(8)));
typedef __bf16 bf16x4 __attribute__((ext_vector_type(4)));
typedef float f32x4 __attribute__((ext_vector_type(4)));

__device__ __forceinline__ float b2f(u16 b) {
    return __builtin_bit_cast(float, ((unsigned)b) << 16);
}
__device__ __forceinline__ u16 f2b(float f) {
    unsigned u = __builtin_bit_cast(unsigned, f);
    return (u16)((u + 0x7fffu + ((u >> 16) & 1u)) >> 16);
}
__device__ __forceinline__ void async16(const void* g, void* l) {
    __builtin_amdgcn_global_load_lds((const __attribute__((address_space(1))) void*)g,
                                     (__attribute__((address_space(3))) void*)l, 16, 0, 0);
}

// ---------------------------------------------------------------- add pe (f32 in)
__global__ __launch_bounds__(256) void add_pe_kernel(const float* __restrict__ x,
                                                     const float* __restrict__ pe,
                                                     float* __restrict__ hf,
                                                     u16* __restrict__ hb) {
    const size_t i = ((size_t)blockIdx.x * 256 + threadIdx.x) * 4;
    float4 xv = *(const float4*)(x + i);
    float4 pv = *(const float4*)(pe + (i & 2097151));  // i mod L*D (2^21)
    float4 f;
    f.x = xv.x + pv.x; f.y = xv.y + pv.y; f.z = xv.z + pv.z; f.w = xv.w + pv.w;
    *(float4*)(hf + i) = f;
    ushort4 hv;
    hv.x = f2b(f.x); hv.y = f2b(f.y); hv.z = f2b(f.z); hv.w = f2b(f.w);
    *(ushort4*)(hb + i) = hv;
}

// ------------------------------------------- transpose+cast (layer-strided):
// src f32 [K, srcStride] -> dst bf16 [N, K]; blockIdx.z selects layer.
__global__ __launch_bounds__(256) void transpose_cast_kernel(const float* __restrict__ src0,
                                                             u16* __restrict__ dst0,
                                                             int srcStride, int K,
                                                             int srcLayer, int dstLayer) {
    __shared__ __align__(16) u16 tile[64 * 72];
    const float* src = src0 + (size_t)blockIdx.z * srcLayer;
    u16* dst = dst0 + (size_t)blockIdx.z * dstLayer;
    const int n0 = blockIdx.x * 64, k0 = blockIdx.y * 64;
    const int t = threadIdx.x;
    const int r = t >> 3, c8 = (t & 7) * 8;
#pragma unroll
    for (int ph = 0; ph < 2; ph++) {
        const int rr = r + ph * 32;
        const float* s = src + (size_t)(k0 + rr) * srcStride + n0 + c8;
        float4 a = *(const float4*)s;
        float4 b = *(const float4*)(s + 4);
        u16* tr = tile + rr * 72 + c8;
        tr[0] = f2b(a.x); tr[1] = f2b(a.y); tr[2] = f2b(a.z); tr[3] = f2b(a.w);
        tr[4] = f2b(b.x); tr[5] = f2b(b.y); tr[6] = f2b(b.z); tr[7] = f2b(b.w);
    }
    __syncthreads();
#pragma unroll
    for (int ph = 0; ph < 2; ph++) {
        const int rr = r + ph * 32;
        union { float4 f; u16 u[8]; } ov;
#pragma unroll
        for (int j = 0; j < 8; j++) ov.u[j] = tile[(c8 + j) * 72 + rr];
        *(float4*)(dst + (size_t)(n0 + rr) * K + k0 + c8) = ov.f;
    }
}

// ------------------------------------------- fused QKV weight transpose, all layers:
// z = layer*3 + mat; 3 x [1024,1024] f32 per layer -> bf16^T [3072,1024] per layer
__global__ __launch_bounds__(256) void transpose_qkv_kernel(const float* __restrict__ wq,
                                                            const float* __restrict__ wk,
                                                            const float* __restrict__ wv,
                                                            u16* __restrict__ dst) {
    __shared__ __align__(16) u16 tile[64 * 72];
    const int zz = blockIdx.z;
    const int l = zz / 3, mat = zz - l * 3;
    const float* src = ((mat == 0) ? wq : (mat == 1) ? wk : wv) + (size_t)l * 1048576;
    u16* d = dst + (size_t)l * 3145728 + (size_t)mat * 1048576;
    const int n0 = blockIdx.x * 64, k0 = blockIdx.y * 64;
    const int t = threadIdx.x;
    const int r = t >> 3, c8 = (t & 7) * 8;
#pragma unroll
    for (int ph = 0; ph < 2; ph++) {
        const int rr = r + ph * 32;
        const float* s = src + (size_t)(k0 + rr) * 1024 + n0 + c8;
        float4 a = *(const float4*)s;
        float4 b = *(const float4*)(s + 4);
        u16* tr = tile + rr * 72 + c8;
        tr[0] = f2b(a.x); tr[1] = f2b(a.y); tr[2] = f2b(a.z); tr[3] = f2b(a.w);
        tr[4] = f2b(b.x); tr[5] = f2b(b.y); tr[6] = f2b(b.z); tr[7] = f2b(b.w);
    }
    __syncthreads();
#pragma unroll
    for (int ph = 0; ph < 2; ph++) {
        const int rr = r + ph * 32;
        union { float4 f; u16 u[8]; } ov;
#pragma unroll
        for (int j = 0; j < 8; j++) ov.u[j] = tile[(c8 + j) * 72 + rr];
        *(float4*)(d + (size_t)(n0 + rr) * 1024 + k0 + c8) = ov.f;
    }
}

// ------------------------------------------- per-head V transpose: [bh][t][64] -> [bh][64][t] (bf16)
__global__ __launch_bounds__(256) void transpose_v_kernel(const u16* __restrict__ src,
                                                          u16* __restrict__ dst) {
    __shared__ __align__(16) u16 tile[64 * 72];
    const int bh = blockIdx.y, t0 = blockIdx.x * 64;
    const int t = threadIdx.x;
    const int r = t >> 3, c8 = (t & 7) * 8;
    const size_t base = (size_t)bh * 131072;
#pragma unroll
    for (int ph = 0; ph < 2; ph++) {
        const int rr = r + ph * 32;
        *(float4*)(tile + rr * 72 + c8) = *(const float4*)(src + base + (size_t)(t0 + rr) * 64 + c8);
    }
    __syncthreads();
#pragma unroll
    for (int ph = 0; ph < 2; ph++) {
        const int rr = r + ph * 32;  // d row
        union { float4 f; u16 u[8]; } ov;
#pragma unroll
        for (int j = 0; j < 8; j++) ov.u[j] = tile[(c8 + j) * 72 + rr];
        *(float4*)(dst + base + (size_t)rr * 2048 + t0 + c8) = ov.f;
    }
}

// ---------------------------------------------------------------- 256x256 8-phase GEMM, BK=64
// C = A[M,Kstride-chunk] * BT[N,Kstride-chunk]^T over NT*64 K-elements starting at
// blockIdx.z * NT*64 (split-K). 8 waves (2M x 4N). Counted vmcnt (T3+T4), LDS XOR
// swizzle via pre-swizzled global source (T2), setprio around MFMA (T5).
// MODE 0: QKV scatter (q pre-scaled by 0.125*log2(e)); MODE 1: bias+selu bf16;
// MODE 4: f32 partial per z-chunk (split-K; reduced in ln_kernel<2>).
#define G_SYNC1()                                          \
    __builtin_amdgcn_sched_barrier(0);                     \
    __builtin_amdgcn_s_barrier();                          \
    asm volatile("s_waitcnt lgkmcnt(0)" ::: "memory");     \
    __builtin_amdgcn_sched_barrier(0);                     \
    __builtin_amdgcn_s_setprio(1)
#define G_SYNC2()                                          \
    __builtin_amdgcn_s_setprio(0);                         \
    __builtin_amdgcn_sched_barrier(0);                     \
    __builtin_amdgcn_s_barrier()

template <int MODE, int NT>
__global__ __launch_bounds__(512) void gemm256_kernel(const u16* __restrict__ A,
                                                      const u16* __restrict__ BT,
                                                      const float* __restrict__ bias,
                                                      void* __restrict__ O0, void* __restrict__ O1,
                                                      void* __restrict__ O2, int N, int Kstride) {
    __shared__ __align__(16) u16 lds[65536];  // 128 KB
    const int tid = threadIdx.x;
    const int lane = tid & 63, w = tid >> 6, quad = lane >> 4, l15 = lane & 15;
    const int wm = w >> 2, wn = w & 3;
    const int m0 = blockIdx.y * 256, n0 = blockIdx.x * 256;
    const size_t koff = (size_t)blockIdx.z * (NT * 64);

    f32x4 acc[8][4] = {};

    // staging: thread t covers granule t (rows 0-127) and 512+t (rows 128-255) of a kh-block
    const int srow = tid >> 2;
    const int slog = (tid & 3) ^ ((tid >> 3) & 3);  // pre-swizzled source slot
    const u16* pA = A + (size_t)(m0 + srow) * Kstride + koff + slog * 8;
    const u16* pB = BT + (size_t)(n0 + srow) * Kstride + koff + slog * 8;
    u16* const ldst = lds + tid * 8;

    // frag-read bases (swizzle key (row>>1)&3 == (l15>>1)&3 since row offsets are x16)
    const int swz = (quad ^ ((l15 >> 1) & 3)) * 8;
    const int aro = (wm * 128 + l15) * 32 + swz;           // + boff + kh*8192 + mh*2048 + mt*512
    const int bro = 16384 + (wn * 64 + l15) * 32 + swz;    // + boff + kh*8192 + nt*512

    auto stA = [&](int tt, int kh) {
        u16* d = ldst + ((tt & 1) << 15) + (kh << 13);
        const u16* s = pA + tt * 64 + kh * 32;
        async16(s, d);
        async16(s + (size_t)128 * Kstride, d + 4096);
    };
    auto stB = [&](int tt, int kh) {
        u16* d = ldst + ((tt & 1) << 15) + 16384 + (kh << 13);
        const u16* s = pB + tt * 64 + kh * 32;
        async16(s, d);
        async16(s + (size_t)128 * Kstride, d + 4096);
    };

    // prologue: tile0 fully, tile1 all but Akh1 (14 per-thread loads)
    stB(0, 0); stB(0, 1); stA(0, 0); stA(0, 1);
    stB(1, 0); stB(1, 1); stA(1, 0);
    asm volatile("s_waitcnt vmcnt(6)" ::: "memory");  // tile0's 8 loads landed
    __builtin_amdgcn_s_barrier();

#pragma unroll 2
    for (int t = 0; t < NT; ++t) {
        const int boff = (t & 1) << 15;
        bf16x8 a[4], bk0[4], bk1[4];
        // ---- phase 0: (kh0, mh0); B kh0 into regs; stage Akh1(t+1)
#pragma unroll
        for (int i = 0; i < 4; i++) a[i] = *(const bf16x8*)(lds + boff + aro + i * 512);
#pragma unroll
        for (int i = 0; i < 4; i++) bk0[i] = *(const bf16x8*)(lds + boff + bro + i * 512);
        if (t + 1 < NT) stA(t + 1, 1);
        G_SYNC1();
#pragma unroll
        for (int mt = 0; mt < 4; mt++)
#pragma unroll
            for (int nt = 0; nt < 4; nt++)
                acc[mt][nt] = __builtin_amdgcn_mfma_f32_16x16x32_bf16(a[mt], bk0[nt], acc[mt][nt], 0, 0, 0);
        G_SYNC2();
        // ---- phase 1: (kh1, mh0); B kh1 into regs; stage Bkh0(t+2)
#pragma unroll
        for (int i = 0; i < 4; i++) a[i] = *(const bf16x8*)(lds + boff + 8192 + aro + i * 512);
#pragma unroll
        for (int i = 0; i < 4; i++) bk1[i] = *(const bf16x8*)(lds + boff + 8192 + bro + i * 512);
        if (t + 2 < NT) stB(t + 2, 0);
        G_SYNC1();
#pragma unroll
        for (int mt = 0; mt < 4; mt++)
#pragma unroll
            for (int nt = 0; nt < 4; nt++)
                acc[mt][nt] = __builtin_amdgcn_mfma_f32_16x16x32_bf16(a[mt], bk1[nt], acc[mt][nt], 0, 0, 0);
        G_SYNC2();
        // ---- phase 2: (kh0, mh1); reuse bk0; stage Bkh1(t+2)
#pragma unroll
        for (int i = 0; i < 4; i++) a[i] = *(const bf16x8*)(lds + boff + aro + 2048 + i * 512);
        if (t + 2 < NT) stB(t + 2, 1);
        G_SYNC1();
#pragma unroll
        for (int mt = 0; mt < 4; mt++)
#pragma unroll
            for (int nt = 0; nt < 4; nt++)
                acc[4 + mt][nt] = __builtin_amdgcn_mfma_f32_16x16x32_bf16(a[mt], bk0[nt], acc[4 + mt][nt], 0, 0, 0);
        G_SYNC2();
        // ---- phase 3: (kh1, mh1); reuse bk1; stage Akh0(t+2); per-tile vmcnt
#pragma unroll
        for (int i = 0; i < 4; i++) a[i] = *(const bf16x8*)(lds + boff + 8192 + aro + 2048 + i * 512);
        if (t + 2 < NT) stA(t + 2, 0);
        G_SYNC1();
#pragma unroll
        for (int mt = 0; mt < 4; mt++)
#pragma unroll
            for (int nt = 0; nt < 4; nt++)
                acc[4 + mt][nt] = __builtin_amdgcn_mfma_f32_16x16x32_bf16(a[mt], bk1[nt], acc[4 + mt][nt], 0, 0, 0);
        __builtin_amdgcn_s_setprio(0);
        __builtin_amdgcn_sched_barrier(0);
        if (t < NT - 2) {
            asm volatile("s_waitcnt vmcnt(6)" ::: "memory");  // tile t+1 fully landed
        } else if (t == NT - 2) {
            asm volatile("s_waitcnt vmcnt(0)" ::: "memory");  // tail: drain last tile
        }
        __builtin_amdgcn_sched_barrier(0);
        __builtin_amdgcn_s_barrier();
    }

#pragma unroll
    for (int nt = 0; nt < 4; nt++) {
        const int col = n0 + wn * 64 + nt * 16 + l15;
        float bv = 0.f;
        if (MODE == 1) bv = bias[col];
#pragma unroll
        for (int am = 0; am < 8; am++) {
#pragma unroll
            for (int r = 0; r < 4; r++) {
                const int row = m0 + wm * 128 + am * 16 + quad * 4 + r;
                float val = acc[am][nt][r];
                if (MODE == 0) {
                    const int mat = col >> 10, cc = col & 1023;
                    const int head = cc >> 6, dh = cc & 63;
                    const int b = row >> 11, tt = row & 2047;
                    if (mat == 0) val *= 0.18033688f;  // 0.125 * log2(e): base-2 softmax domain
                    u16* dst = (mat == 0) ? (u16*)O0 : (mat == 1) ? (u16*)O1 : (u16*)O2;
                    dst[(((size_t)(b * 16 + head)) * 2048 + tt) * 64 + dh] = f2b(val);
                } else if (MODE == 1) {
                    val += bv;
                    const float s = 1.0507009873554805f, aa = 1.6732632423543772f;
                    val = val > 0.f ? s * val : s * aa * (__expf(val) - 1.f);
                    ((u16*)O0)[(size_t)row * N + col] = f2b(val);
                } else if (MODE == 4) {
                    ((float*)O0)[((size_t)blockIdx.z * 4096 + row) * N + col] = val;
                }
            }
        }
    }
}

// ---------------------------------------------------------------- flash attention (causal), S^T form
// Async double-buffered K/V staging via global_load_lds, linear [64][64] tiles with
// 16B-granule XOR swizzle (slot ^= row&7) applied via pre-swizzled GLOBAL source;
// counted vmcnt(4) so tile t+1 loads fly under tile t compute; setprio around MFMA.
__global__ __launch_bounds__(256) void attn_kernel(const u16* __restrict__ q,
                                                   const u16* __restrict__ k,
                                                   const u16* __restrict__ vT,
                                                   u16* __restrict__ o) {
    __shared__ __align__(16) u16 Kt[2][4096];      // [buf][k*64+d swz]
    __shared__ __align__(16) u16 Vt[2][4096];      // [buf][d*64+k swz]
    __shared__ __align__(16) u16 Pt[4][32 * 72];   // per-wave P [q][k]
    const int tid = threadIdx.x, lane = tid & 63, w = tid >> 6, quad = lane >> 4, l15 = lane & 15;
    const int bh = blockIdx.x;
    const int qt = 15 - blockIdx.y;                // LPT: heavy diagonal blocks dispatch first
    const size_t base = (size_t)bh * 131072;
    const int wrow0 = qt * 128 + w * 32;

    // staging precompute: thread covers granules tid and tid+256 of each 512-granule tile
    const int r0 = tid >> 3, s0 = (tid & 7) ^ (r0 & 7);
    const int r1 = (tid + 256) >> 3, s1 = (tid & 7) ^ (r1 & 7);
    const u16* kg0 = k + base + r0 * 64 + s0 * 8;
    const u16* kg1 = k + base + r1 * 64 + s1 * 8;
    const u16* vg0 = vT + base + (size_t)r0 * 2048 + s0 * 8;
    const u16* vg1 = vT + base + (size_t)r1 * 2048 + s1 * 8;

    auto stage = [&](int kt, int b) {
        async16(kg0 + kt * 4096, &Kt[b][tid * 8]);
        async16(kg1 + kt * 4096, &Kt[b][tid * 8 + 2048]);
        async16(vg0 + (size_t)kt * 64, &Vt[b][tid * 8]);
        async16(vg1 + (size_t)kt * 64, &Vt[b][tid * 8 + 2048]);
    };

    // swizzled read slots (row&7 == l15&7 for 16-row-strided frag rows)
    const int sA = (quad ^ (l15 & 7)) * 8;
    const int sB = sA ^ 32;

    bf16x8 qf[2][2];
#pragma unroll
    for (int nt = 0; nt < 2; nt++)
#pragma unroll
        for (int ks = 0; ks < 2; ks++)
            qf[nt][ks] = *(const bf16x8*)(q + base + (size_t)(wrow0 + nt * 16 + l15) * 64 + ks * 32 + quad * 8);

    float m_[2], l_[2];
    m_[0] = m_[1] = -1e30f;
    l_[0] = l_[1] = 0.f;
    f32x4 oacc[2][4] = {};

    const int ktmax = (qt + 1) * 2;
    stage(0, 0);

    for (int kt = 0; kt < ktmax; kt++) {
        const int cur = kt & 1;
        if (kt + 1 < ktmax) {
            stage(kt + 1, cur ^ 1);
            __builtin_amdgcn_sched_barrier(0);
            asm volatile("s_waitcnt vmcnt(4)" ::: "memory");  // tile kt landed; kt+1 in flight
        } else {
            __builtin_amdgcn_sched_barrier(0);
            asm volatile("s_waitcnt vmcnt(0)" ::: "memory");
        }
        __builtin_amdgcn_sched_barrier(0);
        __builtin_amdgcn_s_barrier();
        __builtin_amdgcn_sched_barrier(0);
        const u16* Kb = Kt[cur];
        const u16* Vb = Vt[cur];
        const bool act = (kt * 64 <= wrow0 + 31);
        if (act) {
            f32x4 st[4][2];
            __builtin_amdgcn_s_setprio(1);
#pragma unroll
            for (int mt = 0; mt < 4; mt++) {
                bf16x8 kf0 = *(const bf16x8*)(Kb + (mt * 16 + l15) * 64 + sA);
                bf16x8 kf1 = *(const bf16x8*)(Kb + (mt * 16 + l15) * 64 + sB);
#pragma unroll
                for (int nt = 0; nt < 2; nt++) {
                    f32x4 z = {};
                    z = __builtin_amdgcn_mfma_f32_16x16x32_bf16(kf0, qf[nt][0], z, 0, 0, 0);
                    z = __builtin_amdgcn_mfma_f32_16x16x32_bf16(kf1, qf[nt][1], z, 0, 0, 0);
                    st[mt][nt] = z;
                }
            }
            __builtin_amdgcn_s_setprio(0);
            const bool needmask = (kt * 64 + 63 > wrow0);
            float alpha[2];
#pragma unroll
            for (int nt = 0; nt < 2; nt++) {
                const int qg = wrow0 + nt * 16 + l15;
                float mx = -1e30f;
                if (needmask) {
#pragma unroll
                    for (int mt = 0; mt < 4; mt++)
#pragma unroll
                        for (int r = 0; r < 4; r++) {
                            const int kg = kt * 64 + mt * 16 + quad * 4 + r;
                            float s = (kg <= qg) ? st[mt][nt][r] : -1e30f;
                            st[mt][nt][r] = s;
                            mx = fmaxf(mx, s);
                        }
                } else {
#pragma unroll
                    for (int mt = 0; mt < 4; mt++)
#pragma unroll
                        for (int r = 0; r < 4; r++) mx = fmaxf(mx, st[mt][nt][r]);
                }
                mx = fmaxf(mx, __shfl_xor(mx, 16, 64));
                mx = fmaxf(mx, __shfl_xor(mx, 32, 64));
                const float mnew = fmaxf(m_[nt], mx);
                alpha[nt] = exp2f(m_[nt] - mnew);
                m_[nt] = mnew;
                float rs = 0.f;
#pragma unroll
                for (int mt = 0; mt < 4; mt++) {
                    float p0 = exp2f(st[mt][nt][0] - mnew);
                    float p1 = exp2f(st[mt][nt][1] - mnew);
                    float p2 = exp2f(st[mt][nt][2] - mnew);
                    float p3 = exp2f(st[mt][nt][3] - mnew);
                    rs += (p0 + p1) + (p2 + p3);
                    bf16x4 pk = {(__bf16)p0, (__bf16)p1, (__bf16)p2, (__bf16)p3};
                    *(bf16x4*)(Pt[w] + (nt * 16 + l15) * 72 + mt * 16 + quad * 4) = pk;
                }
                rs += __shfl_xor(rs, 16, 64);
                rs += __shfl_xor(rs, 32, 64);
                l_[nt] = l_[nt] * alpha[nt] + rs;
            }
            float arow[2][4];
#pragma unroll
            for (int mto = 0; mto < 2; mto++)
#pragma unroll
                for (int r = 0; r < 4; r++)
                    arow[mto][r] = __shfl(alpha[mto], quad * 4 + r, 64);
#pragma unroll
            for (int mto = 0; mto < 2; mto++)
#pragma unroll
                for (int ntv = 0; ntv < 4; ntv++)
#pragma unroll
                    for (int r = 0; r < 4; r++) oacc[mto][ntv][r] *= arow[mto][r];

            bf16x8 pf[2][2];
#pragma unroll
            for (int mto = 0; mto < 2; mto++)
#pragma unroll
                for (int ks = 0; ks < 2; ks++)
                    pf[mto][ks] = *(const bf16x8*)(Pt[w] + (mto * 16 + l15) * 72 + ks * 32 + quad * 8);
            __builtin_amdgcn_s_setprio(1);
#pragma unroll
            for (int ntv = 0; ntv < 4; ntv++) {
                bf16x8 vf0 = *(const bf16x8*)(Vb + (ntv * 16 + l15) * 64 + sA);
                bf16x8 vf1 = *(const bf16x8*)(Vb + (ntv * 16 + l15) * 64 + sB);
#pragma unroll
                for (int mto = 0; mto < 2; mto++) {
                    oacc[mto][ntv] = __builtin_amdgcn_mfma_f32_16x16x32_bf16(pf[mto][0], vf0, oacc[mto][ntv], 0, 0, 0);
                    oacc[mto][ntv] = __builtin_amdgcn_mfma_f32_16x16x32_bf16(pf[mto][1], vf1, oacc[mto][ntv], 0, 0, 0);
                }
            }
            __builtin_amdgcn_s_setprio(0);
        }
        __builtin_amdgcn_sched_barrier(0);
        __builtin_amdgcn_s_barrier();
        __builtin_amdgcn_sched_barrier(0);
    }

    float linv[2] = {1.f / l_[0], 1.f / l_[1]};
    float rinv[2][4];
#pragma unroll
    for (int mto = 0; mto < 2; mto++)
#pragma unroll
        for (int r = 0; r < 4; r++)
            rinv[mto][r] = __shfl(linv[mto], quad * 4 + r, 64);

    const int b = bh >> 4, hh = bh & 15;
#pragma unroll
    for (int mto = 0; mto < 2; mto++)
#pragma unroll
        for (int ntv = 0; ntv < 4; ntv++)
#pragma unroll
            for (int r = 0; r < 4; r++) {
                const int trow = wrow0 + mto * 16 + quad * 4 + r;
                const int col = hh * 64 + ntv * 16 + l15;
                o[((size_t)b * 2048 + trow) * 1024 + col] = f2b(oacc[mto][ntv][r] * rinv[mto][r]);
            }
}

// ---------------------------------------------------------------- fused residual-add + layernorm
// AM=1: add one bf16 operand. AM=2: add 4 f32 split-K partials (stride 4096x1024) + bias2.
template <int AM>
__global__ __launch_bounds__(256) void ln_kernel(const float* __restrict__ hin,
                                                 const void* __restrict__ addp,
                                                 const float* __restrict__ g,
                                                 const float* __restrict__ bt,
                                                 const float* __restrict__ bias2,
                                                 float* __restrict__ hf_out,
                                                 u16* __restrict__ hb_out) {
    const int w = threadIdx.x >> 6, lane = threadIdx.x & 63;
    const size_t row = (size_t)blockIdx.x * 4 + w;
    const float4* hr = (const float4*)(hin + row * 1024);
    float4 xv[4];
    float s = 0.f, s2 = 0.f;
#pragma unroll
    for (int j = 0; j < 4; j++) {
        const int idx = lane + 64 * j;
        float4 a = hr[idx];
        float4 b;
        if (AM == 1) {
            ushort4 av = ((const ushort4*)addp)[row * 256 + idx];
            b.x = b2f(av.x); b.y = b2f(av.y); b.z = b2f(av.z); b.w = b2f(av.w);
        } else {
            const float4* pp = (const float4*)addp;
            const size_t po = row * 256 + idx;
            float4 p0 = pp[po];
            float4 p1 = pp[po + 1048576];
            float4 p2 = pp[po + 2097152];
            float4 p3 = pp[po + 3145728];
            float4 bb2 = ((const float4*)bias2)[idx];
            b.x = (p0.x + p1.x) + (p2.x + p3.x) + bb2.x;
            b.y = (p0.y + p1.y) + (p2.y + p3.y) + bb2.y;
            b.z = (p0.z + p1.z) + (p2.z + p3.z) + bb2.z;
            b.w = (p0.w + p1.w) + (p2.w + p3.w) + bb2.w;
        }
        float4 x;
        x.x = a.x + b.x; x.y = a.y + b.y; x.z = a.z + b.z; x.w = a.w + b.w;
        xv[j] = x;
        s += x.x + x.y + x.z + x.w;
        s2 += x.x * x.x + x.y * x.y + x.z * x.z + x.w * x.w;
    }
#pragma unroll
    for (int mm = 1; mm < 64; mm <<= 1) { s += __shfl_xor(s, mm, 64); s2 += __shfl_xor(s2, mm, 64); }
    const float mean = s * (1.f / 1024.f);
    const float var = s2 * (1.f / 1024.f) - mean * mean;
    const float rstd = rsqrtf(var + 1e-5f);
    float4* of = (float4*)(hf_out + row * 1024);
    ushort4* ob = (ushort4*)(hb_out + row * 1024);
    const float4* gv = (const float4*)g;
    const float4* bv = (const float4*)bt;
#pragma unroll
    for (int j = 0; j < 4; j++) {
        const int idx = lane + 64 * j;
        float4 gg = gv[idx], bb = bv[idx];
        float4 x = xv[j], y;
        y.x = (x.x - mean) * rstd * gg.x + bb.x;
        y.y = (x.y - mean) * rstd * gg.y + bb.y;
        y.z = (x.z - mean) * rstd * gg.z + bb.z;
        y.w = (x.w - mean) * rstd * gg.w + bb.w;
        of[idx] = y;
        ushort4 oo;
        oo.x = f2b(y.x); oo.y = f2b(y.y); oo.z = f2b(y.z); oo.w = f2b(y.w);
        ob[idx] = oo;
    }
}

// ---------------------------------------------------------------- host
extern "C" void kernel_launch(void* const* d_in, const int* in_sizes, int n_in,
                              void* d_out, int out_size, void* d_ws, size_t ws_size,
                              hipStream_t stream) {
    const float* x   = (const float*)d_in[0];
    const float* pe  = (const float*)d_in[1];
    const float* wq  = (const float*)d_in[2];
    const float* wk  = (const float*)d_in[3];
    const float* wv  = (const float*)d_in[4];
    const float* l1g = (const float*)d_in[5];
    const float* l1b = (const float*)d_in[6];
    const float* w1  = (const float*)d_in[7];
    const float* b1  = (const float*)d_in[8];
    const float* w2  = (const float*)d_in[9];
    const float* b2  = (const float*)d_in[10];
    const float* l2g = (const float*)d_in[11];
    const float* l2b = (const float*)d_in[12];

    // 328 MB of the 512 MB workspace:
    char* ws = (char*)d_ws;
    float* hf   = (float*)(ws);                   // [  0, 16M) f32 residual stream
    u16* hb     = (u16*)(ws + 16777216);          // [ 16, 24M) bf16 mirror of h
    u16* qb     = (u16*)(ws + 25165824);          // [ 24, 32M) Q bf16 (pre-scaled)
    u16* kb     = (u16*)(ws + 33554432);          // [ 32, 40M) K bf16
    u16* vb     = (u16*)(ws + 41943040);          // [ 40, 48M) V bf16 natural [bh][t][d]
    u16* ob     = (u16*)(ws + 41943040);          //            attn out (aliases vb)
    u16* vbt    = (u16*)(ws + 50331648);          // [ 48, 56M) V^T [bh][d][t]
    u16* ub     = (u16*)(ws + 58720256);          // [ 56, 88M) ffn hidden bf16 [4096,4096]
    float* mb   = (float*)(ws + 92274688);        // [ 88,152M) ffn out f32, 4 split-K partials
    u16* wqkvT  = (u16*)(ws + 159383552);         // [152,200M) qkv weights^T bf16, all layers
    u16* w1T    = (u16*)(ws + 209715200);         // [200,264M) w1^T bf16, all layers
    u16* w2T    = (u16*)(ws + 276824064);         // [264,328M) w2^T bf16, all layers

    add_pe_kernel<<<4096, 256, 0, stream>>>(x, pe, hf, hb);
    // weight prep, all layers up front (removes 24 in-loop launches)
    transpose_qkv_kernel<<<dim3(16, 16, 24), 256, 0, stream>>>(wq, wk, wv, wqkvT);
    transpose_cast_kernel<<<dim3(64, 16, 8), 256, 0, stream>>>(w1, w1T, 4096, 1024, 4194304, 4194304);
    transpose_cast_kernel<<<dim3(16, 64, 8), 256, 0, stream>>>(w2, w2T, 1024, 4096, 4194304, 4194304);

    for (int l = 0; l < 8; l++) {
        gemm256_kernel<0, 16><<<dim3(12, 16), 512, 0, stream>>>(
            hb, wqkvT + (size_t)l * 3145728, nullptr, qb, kb, vb, 3072, 1024);
        transpose_v_kernel<<<dim3(32, 32), 256, 0, stream>>>(vb, vbt);
        attn_kernel<<<dim3(32, 16), 256, 0, stream>>>(qb, kb, vbt, ob);
        ln_kernel<1><<<1024, 256, 0, stream>>>(hf, ob, l1g + l * 1024, l1b + l * 1024, nullptr, hf, hb);
        gemm256_kernel<1, 16><<<dim3(16, 16), 512, 0, stream>>>(
            hb, w1T + (size_t)l * 4194304, b1 + l * 4096, ub, nullptr, nullptr, 4096, 1024);
        gemm256_kernel<4, 16><<<dim3(4, 16, 4), 512, 0, stream>>>(
            ub, w2T + (size_t)l * 4194304, nullptr, mb, nullptr, nullptr, 1024, 4096);
        const bool last = (l == 7);
        ln_kernel<2><<<1024, 256, 0, stream>>>(hf, mb, l2g + l * 1024, l2b + l * 1024,
                                               b2 + l * 1024, last ? (float*)d_out : hf, hb);
    }
}

// Round 3
// 2105.143 us; speedup vs baseline: 1.1968x; 1.0401x over previous
//
#include <hip/hip_runtime.h>
#include <stdint.h>

typedef unsigned short u16;
typedef __bf16 bf16x8 __attribute__((ext_vector_type(8)));
typedef __bf16 bf16x4 __attribute__((ext_vector_type(4)));
typedef float f32x4 __attribute__((ext_vector_type(4)));

__device__ __forceinline__ float b2f(u16 b) {
    return __builtin_bit_cast(float, ((unsigned)b) << 16);
}
__device__ __forceinline__ u16 f2b(float f) {
    unsigned u = __builtin_bit_cast(unsigned, f);
    return (u16)((u + 0x7fffu + ((u >> 16) & 1u)) >> 16);
}
__device__ __forceinline__ void async16(const void* g, void* l) {
    __builtin_amdgcn_global_load_lds((const __attribute__((address_space(1))) void*)g,
                                     (__attribute__((address_space(3))) void*)l, 16, 0, 0);
}

// ---------------------------------------------------------------- add pe (f32 in)
__global__ __launch_bounds__(256) void add_pe_kernel(const float* __restrict__ x,
                                                     const float* __restrict__ pe,
                                                     float* __restrict__ hf,
                                                     u16* __restrict__ hb) {
    const size_t i = ((size_t)blockIdx.x * 256 + threadIdx.x) * 4;
    float4 xv = *(const float4*)(x + i);
    float4 pv = *(const float4*)(pe + (i & 2097151));  // i mod L*D (2^21)
    float4 f;
    f.x = xv.x + pv.x; f.y = xv.y + pv.y; f.z = xv.z + pv.z; f.w = xv.w + pv.w;
    *(float4*)(hf + i) = f;
    ushort4 hv;
    hv.x = f2b(f.x); hv.y = f2b(f.y); hv.z = f2b(f.z); hv.w = f2b(f.w);
    *(ushort4*)(hb + i) = hv;
}

// ------------------------------------------- transpose+cast (layer-strided):
// src f32 [K, srcStride] -> dst bf16 [N, K]; blockIdx.z selects layer.
__global__ __launch_bounds__(256) void transpose_cast_kernel(const float* __restrict__ src0,
                                                             u16* __restrict__ dst0,
                                                             int srcStride, int K,
                                                             int srcLayer, int dstLayer) {
    __shared__ __align__(16) u16 tile[64 * 72];
    const float* src = src0 + (size_t)blockIdx.z * srcLayer;
    u16* dst = dst0 + (size_t)blockIdx.z * dstLayer;
    const int n0 = blockIdx.x * 64, k0 = blockIdx.y * 64;
    const int t = threadIdx.x;
    const int r = t >> 3, c8 = (t & 7) * 8;
#pragma unroll
    for (int ph = 0; ph < 2; ph++) {
        const int rr = r + ph * 32;
        const float* s = src + (size_t)(k0 + rr) * srcStride + n0 + c8;
        float4 a = *(const float4*)s;
        float4 b = *(const float4*)(s + 4);
        u16* tr = tile + rr * 72 + c8;
        tr[0] = f2b(a.x); tr[1] = f2b(a.y); tr[2] = f2b(a.z); tr[3] = f2b(a.w);
        tr[4] = f2b(b.x); tr[5] = f2b(b.y); tr[6] = f2b(b.z); tr[7] = f2b(b.w);
    }
    __syncthreads();
#pragma unroll
    for (int ph = 0; ph < 2; ph++) {
        const int rr = r + ph * 32;
        union { float4 f; u16 u[8]; } ov;
#pragma unroll
        for (int j = 0; j < 8; j++) ov.u[j] = tile[(c8 + j) * 72 + rr];
        *(float4*)(dst + (size_t)(n0 + rr) * K + k0 + c8) = ov.f;
    }
}

// ------------------------------------------- fused QKV weight transpose, all layers:
// z = layer*3 + mat; 3 x [1024,1024] f32 per layer -> bf16^T [3072,1024] per layer
__global__ __launch_bounds__(256) void transpose_qkv_kernel(const float* __restrict__ wq,
                                                            const float* __restrict__ wk,
                                                            const float* __restrict__ wv,
                                                            u16* __restrict__ dst) {
    __shared__ __align__(16) u16 tile[64 * 72];
    const int zz = blockIdx.z;
    const int l = zz / 3, mat = zz - l * 3;
    const float* src = ((mat == 0) ? wq : (mat == 1) ? wk : wv) + (size_t)l * 1048576;
    u16* d = dst + (size_t)l * 3145728 + (size_t)mat * 1048576;
    const int n0 = blockIdx.x * 64, k0 = blockIdx.y * 64;
    const int t = threadIdx.x;
    const int r = t >> 3, c8 = (t & 7) * 8;
#pragma unroll
    for (int ph = 0; ph < 2; ph++) {
        const int rr = r + ph * 32;
        const float* s = src + (size_t)(k0 + rr) * 1024 + n0 + c8;
        float4 a = *(const float4*)s;
        float4 b = *(const float4*)(s + 4);
        u16* tr = tile + rr * 72 + c8;
        tr[0] = f2b(a.x); tr[1] = f2b(a.y); tr[2] = f2b(a.z); tr[3] = f2b(a.w);
        tr[4] = f2b(b.x); tr[5] = f2b(b.y); tr[6] = f2b(b.z); tr[7] = f2b(b.w);
    }
    __syncthreads();
#pragma unroll
    for (int ph = 0; ph < 2; ph++) {
        const int rr = r + ph * 32;
        union { float4 f; u16 u[8]; } ov;
#pragma unroll
        for (int j = 0; j < 8; j++) ov.u[j] = tile[(c8 + j) * 72 + rr];
        *(float4*)(d + (size_t)(n0 + rr) * 1024 + k0 + c8) = ov.f;
    }
}

// ------------------------------------------- per-head V transpose: [bh][t][64] -> [bh][64][t] (bf16)
__global__ __launch_bounds__(256) void transpose_v_kernel(const u16* __restrict__ src,
                                                          u16* __restrict__ dst) {
    __shared__ __align__(16) u16 tile[64 * 72];
    const int bh = blockIdx.y, t0 = blockIdx.x * 64;
    const int t = threadIdx.x;
    const int r = t >> 3, c8 = (t & 7) * 8;
    const size_t base = (size_t)bh * 131072;
#pragma unroll
    for (int ph = 0; ph < 2; ph++) {
        const int rr = r + ph * 32;
        *(float4*)(tile + rr * 72 + c8) = *(const float4*)(src + base + (size_t)(t0 + rr) * 64 + c8);
    }
    __syncthreads();
#pragma unroll
    for (int ph = 0; ph < 2; ph++) {
        const int rr = r + ph * 32;  // d row
        union { float4 f; u16 u[8]; } ov;
#pragma unroll
        for (int j = 0; j < 8; j++) ov.u[j] = tile[(c8 + j) * 72 + rr];
        *(float4*)(dst + base + (size_t)rr * 2048 + t0 + c8) = ov.f;
    }
}

// ---------------------------------------------------------------- 256x256 8-phase GEMM, BK=64
// C = A[M,Kstride-chunk] * BT[N,Kstride-chunk]^T over NT*64 K-elements starting at
// blockIdx.z * NT*64 (split-K). 8 waves (2M x 4N). Counted vmcnt (T3+T4), LDS XOR
// swizzle via pre-swizzled global source (T2), setprio around MFMA (T5).
// MODE 0: QKV scatter (q pre-scaled by 0.125*log2(e)); MODE 1: bias+selu bf16;
// MODE 4: f32 partial per z-chunk (split-K; reduced in ln_kernel<2>).
#define G_SYNC1()                                          \
    __builtin_amdgcn_sched_barrier(0);                     \
    __builtin_amdgcn_s_barrier();                          \
    asm volatile("s_waitcnt lgkmcnt(0)" ::: "memory");     \
    __builtin_amdgcn_sched_barrier(0);                     \
    __builtin_amdgcn_s_setprio(1)
#define G_SYNC2()                                          \
    __builtin_amdgcn_s_setprio(0);                         \
    __builtin_amdgcn_sched_barrier(0);                     \
    __builtin_amdgcn_s_barrier()

template <int MODE, int NT>
__global__ __launch_bounds__(512) void gemm256_kernel(const u16* __restrict__ A,
                                                      const u16* __restrict__ BT,
                                                      const float* __restrict__ bias,
                                                      void* __restrict__ O0, void* __restrict__ O1,
                                                      void* __restrict__ O2, int N, int Kstride) {
    __shared__ __align__(16) u16 lds[65536];  // 128 KB
    const int tid = threadIdx.x;
    const int lane = tid & 63, w = tid >> 6, quad = lane >> 4, l15 = lane & 15;
    const int wm = w >> 2, wn = w & 3;
    const int m0 = blockIdx.y * 256, n0 = blockIdx.x * 256;
    const size_t koff = (size_t)blockIdx.z * (NT * 64);

    f32x4 acc[8][4] = {};

    // staging: thread t covers granule t (rows 0-127) and 512+t (rows 128-255) of a kh-block
    const int srow = tid >> 2;
    const int slog = (tid & 3) ^ ((tid >> 3) & 3);  // pre-swizzled source slot
    const u16* pA = A + (size_t)(m0 + srow) * Kstride + koff + slog * 8;
    const u16* pB = BT + (size_t)(n0 + srow) * Kstride + koff + slog * 8;
    u16* const ldst = lds + tid * 8;

    // frag-read bases (swizzle key (row>>1)&3 == (l15>>1)&3 since row offsets are x16)
    const int swz = (quad ^ ((l15 >> 1) & 3)) * 8;
    const int aro = (wm * 128 + l15) * 32 + swz;           // + boff + kh*8192 + mh*2048 + mt*512
    const int bro = 16384 + (wn * 64 + l15) * 32 + swz;    // + boff + kh*8192 + nt*512

    auto stA = [&](int tt, int kh) {
        u16* d = ldst + ((tt & 1) << 15) + (kh << 13);
        const u16* s = pA + tt * 64 + kh * 32;
        async16(s, d);
        async16(s + (size_t)128 * Kstride, d + 4096);
    };
    auto stB = [&](int tt, int kh) {
        u16* d = ldst + ((tt & 1) << 15) + 16384 + (kh << 13);
        const u16* s = pB + tt * 64 + kh * 32;
        async16(s, d);
        async16(s + (size_t)128 * Kstride, d + 4096);
    };

    // prologue: tile0 fully, tile1 all but Akh1 (14 per-thread loads)
    stB(0, 0); stB(0, 1); stA(0, 0); stA(0, 1);
    stB(1, 0); stB(1, 1); stA(1, 0);
    asm volatile("s_waitcnt vmcnt(6)" ::: "memory");  // tile0's 8 loads landed
    __builtin_amdgcn_s_barrier();

#pragma unroll 2
    for (int t = 0; t < NT; ++t) {
        const int boff = (t & 1) << 15;
        bf16x8 a[4], bk0[4], bk1[4];
        // ---- phase 0: (kh0, mh0); B kh0 into regs; stage Akh1(t+1)
#pragma unroll
        for (int i = 0; i < 4; i++) a[i] = *(const bf16x8*)(lds + boff + aro + i * 512);
#pragma unroll
        for (int i = 0; i < 4; i++) bk0[i] = *(const bf16x8*)(lds + boff + bro + i * 512);
        if (t + 1 < NT) stA(t + 1, 1);
        G_SYNC1();
#pragma unroll
        for (int mt = 0; mt < 4; mt++)
#pragma unroll
            for (int nt = 0; nt < 4; nt++)
                acc[mt][nt] = __builtin_amdgcn_mfma_f32_16x16x32_bf16(a[mt], bk0[nt], acc[mt][nt], 0, 0, 0);
        G_SYNC2();
        // ---- phase 1: (kh1, mh0); B kh1 into regs; stage Bkh0(t+2)
#pragma unroll
        for (int i = 0; i < 4; i++) a[i] = *(const bf16x8*)(lds + boff + 8192 + aro + i * 512);
#pragma unroll
        for (int i = 0; i < 4; i++) bk1[i] = *(const bf16x8*)(lds + boff + 8192 + bro + i * 512);
        if (t + 2 < NT) stB(t + 2, 0);
        G_SYNC1();
#pragma unroll
        for (int mt = 0; mt < 4; mt++)
#pragma unroll
            for (int nt = 0; nt < 4; nt++)
                acc[mt][nt] = __builtin_amdgcn_mfma_f32_16x16x32_bf16(a[mt], bk1[nt], acc[mt][nt], 0, 0, 0);
        G_SYNC2();
        // ---- phase 2: (kh0, mh1); reuse bk0; stage Bkh1(t+2)
#pragma unroll
        for (int i = 0; i < 4; i++) a[i] = *(const bf16x8*)(lds + boff + aro + 2048 + i * 512);
        if (t + 2 < NT) stB(t + 2, 1);
        G_SYNC1();
#pragma unroll
        for (int mt = 0; mt < 4; mt++)
#pragma unroll
            for (int nt = 0; nt < 4; nt++)
                acc[4 + mt][nt] = __builtin_amdgcn_mfma_f32_16x16x32_bf16(a[mt], bk0[nt], acc[4 + mt][nt], 0, 0, 0);
        G_SYNC2();
        // ---- phase 3: (kh1, mh1); reuse bk1; stage Akh0(t+2); per-tile vmcnt
#pragma unroll
        for (int i = 0; i < 4; i++) a[i] = *(const bf16x8*)(lds + boff + 8192 + aro + 2048 + i * 512);
        if (t + 2 < NT) stA(t + 2, 0);
        G_SYNC1();
#pragma unroll
        for (int mt = 0; mt < 4; mt++)
#pragma unroll
            for (int nt = 0; nt < 4; nt++)
                acc[4 + mt][nt] = __builtin_amdgcn_mfma_f32_16x16x32_bf16(a[mt], bk1[nt], acc[4 + mt][nt], 0, 0, 0);
        __builtin_amdgcn_s_setprio(0);
        __builtin_amdgcn_sched_barrier(0);
        if (t < NT - 2) {
            asm volatile("s_waitcnt vmcnt(6)" ::: "memory");  // tile t+1 fully landed
        } else if (t == NT - 2) {
            asm volatile("s_waitcnt vmcnt(0)" ::: "memory");  // tail: drain last tile
        }
        __builtin_amdgcn_sched_barrier(0);
        __builtin_amdgcn_s_barrier();
    }

#pragma unroll
    for (int nt = 0; nt < 4; nt++) {
        const int col = n0 + wn * 64 + nt * 16 + l15;
        float bv = 0.f;
        if (MODE == 1) bv = bias[col];
#pragma unroll
        for (int am = 0; am < 8; am++) {
#pragma unroll
            for (int r = 0; r < 4; r++) {
                const int row = m0 + wm * 128 + am * 16 + quad * 4 + r;
                float val = acc[am][nt][r];
                if (MODE == 0) {
                    const int mat = col >> 10, cc = col & 1023;
                    const int head = cc >> 6, dh = cc & 63;
                    const int b = row >> 11, tt = row & 2047;
                    if (mat == 0) val *= 0.18033688f;  // 0.125 * log2(e): base-2 softmax domain
                    u16* dst = (mat == 0) ? (u16*)O0 : (mat == 1) ? (u16*)O1 : (u16*)O2;
                    dst[(((size_t)(b * 16 + head)) * 2048 + tt) * 64 + dh] = f2b(val);
                } else if (MODE == 1) {
                    val += bv;
                    const float s = 1.0507009873554805f, aa = 1.6732632423543772f;
                    val = val > 0.f ? s * val : s * aa * (__expf(val) - 1.f);
                    ((u16*)O0)[(size_t)row * N + col] = f2b(val);
                } else if (MODE == 4) {
                    ((float*)O0)[((size_t)blockIdx.z * 4096 + row) * N + col] = val;
                }
            }
        }
    }
}

// ---------------------------------------------------------------- flash attention (causal), S^T form
// QBLK=64 (2 waves/block), grid (bh, 32) LPT. Async double-buffered K/V via
// global_load_lds with 16B-granule XOR swizzle (pre-swizzled global source);
// swizzled per-wave P buffer (stride 64 + granule XOR); defer-max (THR=8, base-2);
// counted vmcnt(8); setprio around MFMA. LDS = 40KB -> 4 blocks/CU.
__global__ __launch_bounds__(128) void attn_kernel(const u16* __restrict__ q,
                                                   const u16* __restrict__ k,
                                                   const u16* __restrict__ vT,
                                                   u16* __restrict__ o) {
    __shared__ __align__(16) u16 Kt[2][4096];      // [buf][k*64+d swz]   16KB
    __shared__ __align__(16) u16 Vt[2][4096];      // [buf][d*64+k swz]   16KB
    __shared__ __align__(16) u16 Pt[2][2048];      // per-wave P [q][k swz] 8KB
    const int tid = threadIdx.x, lane = tid & 63, w = tid >> 6, quad = lane >> 4, l15 = lane & 15;
    const int bh = blockIdx.x;
    const int qb = 31 - blockIdx.y;                // LPT: heavy diagonal blocks dispatch first
    const size_t base = (size_t)bh * 131072;
    const int wrow0 = qb * 64 + w * 32;
    const int ktmax = qb + 1;

    // staging: 128 threads x 4 granules(16B) per tile for K and V each (8 async16/thread)
    const int sr = tid >> 3;                        // base row 0..15 (+16i)
    const int ss = (tid & 7) ^ (sr & 7);            // pre-swizzled source slot
    const u16* kg = k + base + sr * 64 + ss * 8;
    const u16* vg = vT + base + (size_t)sr * 2048 + ss * 8;

    auto stage = [&](int kt, int b) {
#pragma unroll
        for (int i = 0; i < 4; i++)
            async16(kg + kt * 4096 + i * 1024, &Kt[b][tid * 8 + i * 1024]);
#pragma unroll
        for (int i = 0; i < 4; i++)
            async16(vg + kt * 64 + i * 32768, &Vt[b][tid * 8 + i * 1024]);
    };

    // swizzled read slots (row&7 == l15&7 for 16-row-strided frag rows)
    const int sA = (quad ^ (l15 & 7)) * 8;
    const int sB = sA ^ 32;
    const int lx = l15 & 7, qh = quad >> 1, qlow = quad & 1;

    bf16x8 qf[2][2];
#pragma unroll
    for (int nt = 0; nt < 2; nt++)
#pragma unroll
        for (int ks = 0; ks < 2; ks++)
            qf[nt][ks] = *(const bf16x8*)(q + base + (size_t)(wrow0 + nt * 16 + l15) * 64 + ks * 32 + quad * 8);

    float m_[2], l_[2];
    m_[0] = m_[1] = -1e30f;
    l_[0] = l_[1] = 0.f;
    f32x4 oacc[2][4] = {};

    stage(0, 0);

    for (int kt = 0; kt < ktmax; kt++) {
        const int cur = kt & 1;
        if (kt + 1 < ktmax) {
            stage(kt + 1, cur ^ 1);
            __builtin_amdgcn_sched_barrier(0);
            asm volatile("s_waitcnt vmcnt(8)" ::: "memory");  // tile kt landed; kt+1 in flight
        } else {
            __builtin_amdgcn_sched_barrier(0);
            asm volatile("s_waitcnt vmcnt(0)" ::: "memory");
        }
        __builtin_amdgcn_sched_barrier(0);
        __builtin_amdgcn_s_barrier();
        __builtin_amdgcn_sched_barrier(0);
        const u16* Kb = Kt[cur];
        const u16* Vb = Vt[cur];
        {
            f32x4 st[4][2];
            __builtin_amdgcn_s_setprio(1);
#pragma unroll
            for (int mt = 0; mt < 4; mt++) {
                bf16x8 kf0 = *(const bf16x8*)(Kb + (mt * 16 + l15) * 64 + sA);
                bf16x8 kf1 = *(const bf16x8*)(Kb + (mt * 16 + l15) * 64 + sB);
#pragma unroll
                for (int nt = 0; nt < 2; nt++) {
                    f32x4 z = {};
                    z = __builtin_amdgcn_mfma_f32_16x16x32_bf16(kf0, qf[nt][0], z, 0, 0, 0);
                    z = __builtin_amdgcn_mfma_f32_16x16x32_bf16(kf1, qf[nt][1], z, 0, 0, 0);
                    st[mt][nt] = z;
                }
            }
            __builtin_amdgcn_s_setprio(0);
            const bool needmask = (kt == qb);      // wave-uniform: only the diagonal tile
            float alpha[2];
            int needresc = 0;
#pragma unroll
            for (int nt = 0; nt < 2; nt++) {
                const int qg = wrow0 + nt * 16 + l15;
                float mx = -1e30f;
                if (needmask) {
#pragma unroll
                    for (int mt = 0; mt < 4; mt++)
#pragma unroll
                        for (int r = 0; r < 4; r++) {
                            const int kg2 = kt * 64 + mt * 16 + quad * 4 + r;
                            float s = (kg2 <= qg) ? st[mt][nt][r] : -1e30f;
                            st[mt][nt][r] = s;
                            mx = fmaxf(mx, s);
                        }
                } else {
#pragma unroll
                    for (int mt = 0; mt < 4; mt++)
#pragma unroll
                        for (int r = 0; r < 4; r++) mx = fmaxf(mx, st[mt][nt][r]);
                }
                mx = fmaxf(mx, __shfl_xor(mx, 16, 64));
                mx = fmaxf(mx, __shfl_xor(mx, 32, 64));
                const float mold = m_[nt];
                const float mnew = (mx > mold + 8.f) ? mx : mold;  // defer-max (T13)
                alpha[nt] = exp2f(mold - mnew);
                m_[nt] = mnew;
                needresc |= (mnew != mold) ? 1 : 0;
                float rs = 0.f;
#pragma unroll
                for (int mt = 0; mt < 4; mt++) {
                    float p0 = exp2f(st[mt][nt][0] - mnew);
                    float p1 = exp2f(st[mt][nt][1] - mnew);
                    float p2 = exp2f(st[mt][nt][2] - mnew);
                    float p3 = exp2f(st[mt][nt][3] - mnew);
                    rs += (p0 + p1) + (p2 + p3);
                    bf16x4 pk = {(__bf16)p0, (__bf16)p1, (__bf16)p2, (__bf16)p3};
                    // swizzled P store: granule (2mt+qh) ^ (row&7), 8B half by quad parity
                    *(bf16x4*)(Pt[w] + (nt * 16 + l15) * 64 + 8 * ((2 * mt + qh) ^ lx) + 4 * qlow) = pk;
                }
                rs += __shfl_xor(rs, 16, 64);
                rs += __shfl_xor(rs, 32, 64);
                l_[nt] = l_[nt] * alpha[nt] + rs;
            }
            if (__any(needresc)) {                 // skipped on deferred tiles
                float arow[2][4];
#pragma unroll
                for (int mto = 0; mto < 2; mto++)
#pragma unroll
                    for (int r = 0; r < 4; r++)
                        arow[mto][r] = __shfl(alpha[mto], quad * 4 + r, 64);
#pragma unroll
                for (int mto = 0; mto < 2; mto++)
#pragma unroll
                    for (int ntv = 0; ntv < 4; ntv++)
#pragma unroll
                        for (int r = 0; r < 4; r++) oacc[mto][ntv][r] *= arow[mto][r];
            }

            bf16x8 pf[2][2];
#pragma unroll
            for (int mto = 0; mto < 2; mto++)
#pragma unroll
                for (int ks = 0; ks < 2; ks++)
                    pf[mto][ks] = *(const bf16x8*)(Pt[w] + (mto * 16 + l15) * 64 + 8 * ((4 * ks + quad) ^ lx));
            __builtin_amdgcn_s_setprio(1);
#pragma unroll
            for (int ntv = 0; ntv < 4; ntv++) {
                bf16x8 vf0 = *(const bf16x8*)(Vb + (ntv * 16 + l15) * 64 + sA);
                bf16x8 vf1 = *(const bf16x8*)(Vb + (ntv * 16 + l15) * 64 + sB);
#pragma unroll
                for (int mto = 0; mto < 2; mto++) {
                    oacc[mto][ntv] = __builtin_amdgcn_mfma_f32_16x16x32_bf16(pf[mto][0], vf0, oacc[mto][ntv], 0, 0, 0);
                    oacc[mto][ntv] = __builtin_amdgcn_mfma_f32_16x16x32_bf16(pf[mto][1], vf1, oacc[mto][ntv], 0, 0, 0);
                }
            }
            __builtin_amdgcn_s_setprio(0);
        }
        __builtin_amdgcn_sched_barrier(0);
        __builtin_amdgcn_s_barrier();
        __builtin_amdgcn_sched_barrier(0);
    }

    float linv[2] = {1.f / l_[0], 1.f / l_[1]};
    float rinv[2][4];
#pragma unroll
    for (int mto = 0; mto < 2; mto++)
#pragma unroll
        for (int r = 0; r < 4; r++)
            rinv[mto][r] = __shfl(linv[mto], quad * 4 + r, 64);

    const int b = bh >> 4, hh = bh & 15;
#pragma unroll
    for (int mto = 0; mto < 2; mto++)
#pragma unroll
        for (int ntv = 0; ntv < 4; ntv++)
#pragma unroll
            for (int r = 0; r < 4; r++) {
                const int trow = wrow0 + mto * 16 + quad * 4 + r;
                const int col = hh * 64 + ntv * 16 + l15;
                o[((size_t)b * 2048 + trow) * 1024 + col] = f2b(oacc[mto][ntv][r] * rinv[mto][r]);
            }
}

// ---------------------------------------------------------------- fused residual-add + layernorm
// AM=1: add one bf16 operand. AM=2: add 4 f32 split-K partials (stride 4096x1024) + bias2.
template <int AM>
__global__ __launch_bounds__(256) void ln_kernel(const float* __restrict__ hin,
                                                 const void* __restrict__ addp,
                                                 const float* __restrict__ g,
                                                 const float* __restrict__ bt,
                                                 const float* __restrict__ bias2,
                                                 float* __restrict__ hf_out,
                                                 u16* __restrict__ hb_out) {
    const int w = threadIdx.x >> 6, lane = threadIdx.x & 63;
    const size_t row = (size_t)blockIdx.x * 4 + w;
    const float4* hr = (const float4*)(hin + row * 1024);
    float4 xv[4];
    float s = 0.f, s2 = 0.f;
#pragma unroll
    for (int j = 0; j < 4; j++) {
        const int idx = lane + 64 * j;
        float4 a = hr[idx];
        float4 b;
        if (AM == 1) {
            ushort4 av = ((const ushort4*)addp)[row * 256 + idx];
            b.x = b2f(av.x); b.y = b2f(av.y); b.z = b2f(av.z); b.w = b2f(av.w);
        } else {
            const float4* pp = (const float4*)addp;
            const size_t po = row * 256 + idx;
            float4 p0 = pp[po];
            float4 p1 = pp[po + 1048576];
            float4 p2 = pp[po + 2097152];
            float4 p3 = pp[po + 3145728];
            float4 bb2 = ((const float4*)bias2)[idx];
            b.x = (p0.x + p1.x) + (p2.x + p3.x) + bb2.x;
            b.y = (p0.y + p1.y) + (p2.y + p3.y) + bb2.y;
            b.z = (p0.z + p1.z) + (p2.z + p3.z) + bb2.z;
            b.w = (p0.w + p1.w) + (p2.w + p3.w) + bb2.w;
        }
        float4 x;
        x.x = a.x + b.x; x.y = a.y + b.y; x.z = a.z + b.z; x.w = a.w + b.w;
        xv[j] = x;
        s += x.x + x.y + x.z + x.w;
        s2 += x.x * x.x + x.y * x.y + x.z * x.z + x.w * x.w;
    }
#pragma unroll
    for (int mm = 1; mm < 64; mm <<= 1) { s += __shfl_xor(s, mm, 64); s2 += __shfl_xor(s2, mm, 64); }
    const float mean = s * (1.f / 1024.f);
    const float var = s2 * (1.f / 1024.f) - mean * mean;
    const float rstd = rsqrtf(var + 1e-5f);
    float4* of = (float4*)(hf_out + row * 1024);
    ushort4* ob = (ushort4*)(hb_out + row * 1024);
    const float4* gv = (const float4*)g;
    const float4* bv = (const float4*)bt;
#pragma unroll
    for (int j = 0; j < 4; j++) {
        const int idx = lane + 64 * j;
        float4 gg = gv[idx], bb = bv[idx];
        float4 x = xv[j], y;
        y.x = (x.x - mean) * rstd * gg.x + bb.x;
        y.y = (x.y - mean) * rstd * gg.y + bb.y;
        y.z = (x.z - mean) * rstd * gg.z + bb.z;
        y.w = (x.w - mean) * rstd * gg.w + bb.w;
        of[idx] = y;
        ushort4 oo;
        oo.x = f2b(y.x); oo.y = f2b(y.y); oo.z = f2b(y.z); oo.w = f2b(y.w);
        ob[idx] = oo;
    }
}

// ---------------------------------------------------------------- host
extern "C" void kernel_launch(void* const* d_in, const int* in_sizes, int n_in,
                              void* d_out, int out_size, void* d_ws, size_t ws_size,
                              hipStream_t stream) {
    const float* x   = (const float*)d_in[0];
    const float* pe  = (const float*)d_in[1];
    const float* wq  = (const float*)d_in[2];
    const float* wk  = (const float*)d_in[3];
    const float* wv  = (const float*)d_in[4];
    const float* l1g = (const float*)d_in[5];
    const float* l1b = (const float*)d_in[6];
    const float* w1  = (const float*)d_in[7];
    const float* b1  = (const float*)d_in[8];
    const float* w2  = (const float*)d_in[9];
    const float* b2  = (const float*)d_in[10];
    const float* l2g = (const float*)d_in[11];
    const float* l2b = (const float*)d_in[12];

    // 328 MB of the 512 MB workspace:
    char* ws = (char*)d_ws;
    float* hf   = (float*)(ws);                   // [  0, 16M) f32 residual stream
    u16* hb     = (u16*)(ws + 16777216);          // [ 16, 24M) bf16 mirror of h
    u16* qb     = (u16*)(ws + 25165824);          // [ 24, 32M) Q bf16 (pre-scaled)
    u16* kb     = (u16*)(ws + 33554432);          // [ 32, 40M) K bf16
    u16* vb     = (u16*)(ws + 41943040);          // [ 40, 48M) V bf16 natural [bh][t][d]
    u16* ob     = (u16*)(ws + 41943040);          //            attn out (aliases vb)
    u16* vbt    = (u16*)(ws + 50331648);          // [ 48, 56M) V^T [bh][d][t]
    u16* ub     = (u16*)(ws + 58720256);          // [ 56, 88M) ffn hidden bf16 [4096,4096]
    float* mb   = (float*)(ws + 92274688);        // [ 88,152M) ffn out f32, 4 split-K partials
    u16* wqkvT  = (u16*)(ws + 159383552);         // [152,200M) qkv weights^T bf16, all layers
    u16* w1T    = (u16*)(ws + 209715200);         // [200,264M) w1^T bf16, all layers
    u16* w2T    = (u16*)(ws + 276824064);         // [264,328M) w2^T bf16, all layers

    add_pe_kernel<<<4096, 256, 0, stream>>>(x, pe, hf, hb);
    // weight prep, all layers up front
    transpose_qkv_kernel<<<dim3(16, 16, 24), 256, 0, stream>>>(wq, wk, wv, wqkvT);
    transpose_cast_kernel<<<dim3(64, 16, 8), 256, 0, stream>>>(w1, w1T, 4096, 1024, 4194304, 4194304);
    transpose_cast_kernel<<<dim3(16, 64, 8), 256, 0, stream>>>(w2, w2T, 1024, 4096, 4194304, 4194304);

    for (int l = 0; l < 8; l++) {
        gemm256_kernel<0, 16><<<dim3(12, 16), 512, 0, stream>>>(
            hb, wqkvT + (size_t)l * 3145728, nullptr, qb, kb, vb, 3072, 1024);
        transpose_v_kernel<<<dim3(32, 32), 256, 0, stream>>>(vb, vbt);
        attn_kernel<<<dim3(32, 32), 128, 0, stream>>>(qb, kb, vbt, ob);
        ln_kernel<1><<<1024, 256, 0, stream>>>(hf, ob, l1g + l * 1024, l1b + l * 1024, nullptr, hf, hb);
        gemm256_kernel<1, 16><<<dim3(16, 16), 512, 0, stream>>>(
            hb, w1T + (size_t)l * 4194304, b1 + l * 4096, ub, nullptr, nullptr, 4096, 1024);
        gemm256_kernel<4, 16><<<dim3(4, 16, 4), 512, 0, stream>>>(
            ub, w2T + (size_t)l * 4194304, nullptr, mb, nullptr, nullptr, 1024, 4096);
        const bool last = (l == 7);
        ln_kernel<2><<<1024, 256, 0, stream>>>(hf, mb, l2g + l * 1024, l2b + l * 1024,
                                               b2 + l * 1024, last ? (float*)d_out : hf, hb);
    }
}